// Round 1
// baseline (290.050 us; speedup 1.0000x reference)
//
#include <hip/hip_runtime.h>

// MeanShift++ dense-grid, distinct-bin formulation, v13 = v12 (246us)
// + k_compactM eliminated: run-leader's atomicOr RETURN identifies the
//   first-setter of each mask bit -> wave-aggregated direct append to the
//   next step's list (ballot + 1 atomicAdd/wave + popcll rank). Mask words
//   are cleared by the NEXT fused kernel's misc blocks via the same list
//   (every set bit has exactly one first-setter => list covers all words).
// + k_fin folded into k_map (per-point gather through epos/REa directly).
// Identity 1: ref pipeline == 5-tap triangular conv [1,2,3,2,1]^3 over per-bin
// sums/counts. Identity 2: result depends only on bin => per-step work is per
// OCCUPIED BIN; per-point state via 1-tap lookups.
// Dead levers (measured): region-LDS-tile conv (r11, -52%), flattened-tap
// 8-lane conv (r8, -78%), XCD chunk partition (r12, neutral; kept, harmless).

constexpr float BW   = 0.1f;
constexpr float TOL2 = 1e-6f;            // (1e-3)^2
constexpr int DIM  = 112, OFF = 56;      // bins in [-56,55]; |x|<5.6 covered
constexpr int DIM2 = DIM * DIM;
constexpr int CELLS = DIM * DIM * DIM;   // 1,404,928
constexpr int CLW = CELLS / 32;          // 43,904 mask words
constexpr int RDIM = 16, RC = 7;         // 16^3 regions of 7^3 cells
constexpr int NREG = RDIM * RDIM * RDIM; // 4096
constexpr int RC3 = RC * RC * RC;        // 343
constexpr int NB_A = 128, BLK = 256;
constexpr int NF = 2048;                 // k_fused grid
constexpr int IPB = 51;                  // conv items per block (51*5=255 thr)
constexpr float FPS = 16777216.0f;       // 2^24 fixed-point scale
constexpr double FPSI = 1.0 / 16777216.0;

typedef float vf2 __attribute__((ext_vector_type(2)));

__device__ __forceinline__ int clampb(int v) { return v < 0 ? 0 : (v > DIM - 1 ? DIM - 1 : v); }
__device__ __forceinline__ int binf(float v) { return clampb((int)(v / BW) + OFF); }  // IEEE div+trunc == ref
__device__ __forceinline__ int flatb(int bx, int by, int bz) { return (bx * DIM + by) * DIM + bz; }
__device__ __forceinline__ int regOf(int bx, int by, int bz) {
    return ((bx / RC) * RDIM + (by / RC)) * RDIM + (bz / RC);
}
__device__ __forceinline__ int lcOf(int bx, int by, int bz) {
    return ((bx % RC) * RC + (by % RC)) * RC + (bz % RC);
}

__device__ __forceinline__ void pk_add(float* p, float a, float b) {
#if defined(__has_builtin) && __has_builtin(__builtin_amdgcn_global_atomic_fadd_v2f32)
    vf2 v = {a, b};
    __builtin_amdgcn_global_atomic_fadd_v2f32((vf2*)p, v);
#else
    atomicAdd(p, a);
    atomicAdd(p + 1, b);
#endif
}

// ---- pass A1: per-block region histogram (LDS) + streaming zero of grids A,B ----
__launch_bounds__(BLK)
__global__ void k_histA(const float* __restrict__ X, int n, int* __restrict__ blockHist,
                        float4* __restrict__ zeroA, float4* __restrict__ zeroB) {
    __shared__ int h[NREG];
    for (int i = threadIdx.x; i < NREG; i += blockDim.x) h[i] = 0;
    __syncthreads();
    int stride = gridDim.x * blockDim.x;
    for (int i = blockIdx.x * blockDim.x + threadIdx.x; i < n; i += stride) {
        float x = X[3 * i + 0], y = X[3 * i + 1], z = X[3 * i + 2];
        atomicAdd(&h[regOf(binf(x), binf(y), binf(z))], 1);
    }
    __syncthreads();
    for (int i = threadIdx.x; i < NREG; i += blockDim.x)
        blockHist[blockIdx.x * NREG + i] = h[i];
    for (int i = blockIdx.x * blockDim.x + threadIdx.x; i < CELLS; i += stride) {
        zeroA[i] = make_float4(0.f, 0.f, 0.f, 0.f);
        zeroB[i] = make_float4(0.f, 0.f, 0.f, 0.f);
    }
}

// ---- pass A2: per-region column scan over blocks ----
__global__ void k_colscan(int* __restrict__ blockHist, int* __restrict__ regionPS) {
    int r = blockIdx.x * blockDim.x + threadIdx.x;
    if (r >= NREG) return;
    int run = 0;
    for (int b = 0; b < NB_A; ++b) {
        int idx = b * NREG + r;
        int v = blockHist[idx];
        blockHist[idx] = run;
        run += v;
    }
    regionPS[r] = run;
}

// ---- pass A3: exclusive prefix over 4096 region totals ----
__launch_bounds__(1024)
__global__ void k_regprefix(int* __restrict__ regionPS) {
    __shared__ int buf[1024];
    int t = threadIdx.x;
    int v0 = regionPS[4 * t + 0], v1 = regionPS[4 * t + 1];
    int v2 = regionPS[4 * t + 2], v3 = regionPS[4 * t + 3];
    int s = v0 + v1 + v2 + v3;
    buf[t] = s;
    __syncthreads();
    for (int d = 1; d < 1024; d <<= 1) {
        int add = (t >= d) ? buf[t - d] : 0;
        __syncthreads();
        buf[t] += add;
        __syncthreads();
    }
    int excl = buf[t] - s;
    regionPS[4 * t + 0] = excl;
    regionPS[4 * t + 1] = excl + v0;
    regionPS[4 * t + 2] = excl + v0 + v1;
    regionPS[4 * t + 3] = excl + v0 + v1 + v2;
    if (t == 1023) regionPS[4096] = buf[1023];
}

// ---- pass A4: scatter points into region buckets + streaming zero of grid C ----
__launch_bounds__(BLK)
__global__ void k_scatterA(const float* __restrict__ X, int n,
                           const int* __restrict__ blockHist,
                           const int* __restrict__ regionPS,
                           float4* __restrict__ bucket, float4* __restrict__ zeroC) {
    __shared__ int cur[NREG];
    for (int i = threadIdx.x; i < NREG; i += blockDim.x) cur[i] = 0;
    __syncthreads();
    int stride = gridDim.x * blockDim.x;
    for (int i = blockIdx.x * blockDim.x + threadIdx.x; i < n; i += stride) {
        float x = X[3 * i + 0], y = X[3 * i + 1], z = X[3 * i + 2];
        int r = regOf(binf(x), binf(y), binf(z));
        int pos = regionPS[r] + blockHist[blockIdx.x * NREG + r] + atomicAdd(&cur[r], 1);
        bucket[pos] = make_float4(x, y, z, __int_as_float(i));
    }
    for (int i = blockIdx.x * blockDim.x + threadIdx.x; i < CELLS; i += stride)
        zeroC[i] = make_float4(0.f, 0.f, 0.f, 0.f);
}

// ---- pass B: one block/region — LDS int-atomic accumulate, compact, PIdx ----
__launch_bounds__(BLK)
__global__ void k_binB(const float4* __restrict__ bucket, const int* __restrict__ regionPS,
                       float4* __restrict__ A, int* __restrict__ E0,
                       int* __restrict__ PIdx, int* __restrict__ gM0) {
    __shared__ unsigned long long aX[RC3], aY[RC3], aZ[RC3];
    __shared__ unsigned aC[RC3];
    __shared__ int cidx[RC3];
    __shared__ int cnt, cur, sBase;
    int r = blockIdx.x;
    for (int c = threadIdx.x; c < RC3; c += blockDim.x) {
        aX[c] = 0ull; aY[c] = 0ull; aZ[c] = 0ull; aC[c] = 0u;
    }
    if (threadIdx.x == 0) { cnt = 0; cur = 0; }
    __syncthreads();
    int start = regionPS[r], end = regionPS[r + 1];
    for (int i = start + threadIdx.x; i < end; i += blockDim.x) {
        float4 p = bucket[i];
        int lc = lcOf(binf(p.x), binf(p.y), binf(p.z));
        atomicAdd(&aX[lc], (unsigned long long)(long long)rintf(p.x * FPS));
        atomicAdd(&aY[lc], (unsigned long long)(long long)rintf(p.y * FPS));
        atomicAdd(&aZ[lc], (unsigned long long)(long long)rintf(p.z * FPS));
        atomicAdd(&aC[lc], 1u);
    }
    __syncthreads();
    int myc = 0;
    for (int c = threadIdx.x; c < RC3; c += blockDim.x)
        if (aC[c] > 0u) ++myc;
    if (myc) atomicAdd(&cnt, myc);
    __syncthreads();
    if (threadIdx.x == 0 && cnt > 0) sBase = atomicAdd(gM0, cnt);
    __syncthreads();
    int rx = r / (RDIM * RDIM), ry = (r / RDIM) % RDIM, rz = r % RDIM;
    for (int c = threadIdx.x; c < RC3; c += blockDim.x) {
        if (aC[c] > 0u) {
            int idx = sBase + atomicAdd(&cur, 1);
            cidx[c] = idx;
            int bx = rx * RC + c / (RC * RC);
            int by = ry * RC + (c / RC) % RC;
            int bz = rz * RC + c % RC;
            int b = flatb(bx, by, bz);
            E0[idx] = b;
            A[b] = make_float4((float)((double)(long long)aX[c] * FPSI),
                               (float)((double)(long long)aY[c] * FPSI),
                               (float)((double)(long long)aZ[c] * FPSI),
                               (float)aC[c]);
        }
    }
    __syncthreads();
    for (int i = start + threadIdx.x; i < end; i += blockDim.x) {
        float4 p = bucket[i];
        int lc = lcOf(binf(p.x), binf(p.y), binf(p.z));
        PIdx[__float_as_int(p.w)] = cidx[lc];
    }
}

// ---- fused per-step kernel ----
// Blocks [0, BC): conv, 51 items/chunk, 5 threads/item (one dx-plane each),
//   row-contiguous taps, LDS reduce; finalize by wave 0 with head-flag
//   segmented dedup (adjacent equal targets merge; leaders issue atomics).
//   Run leaders whose atomicOr FIRST set the mask bit append the bin to
//   listOut (wave-aggregated: ballot + one atomicAdd + popcll rank) — this
//   replaces the old k_compactM pass entirely.
// Blocks [BC, NF): grid-stride misc (upd / targeted grid clear / targeted
//   mask-word clear via the previous step's list).
__launch_bounds__(BLK)
__global__ void k_fused(
    const float4* __restrict__ src, const int* __restrict__ list, const int* __restrict__ pK,
    float4* __restrict__ REo, int* __restrict__ IDXo, float4* __restrict__ eposInit,
    float4* __restrict__ tgt, unsigned* __restrict__ clT,
    int* __restrict__ listOut, int* __restrict__ pKout,
    int updS, const float* __restrict__ X, int n, const int* __restrict__ PIdx,
    const float4* __restrict__ REp, const int* __restrict__ IDXp,
    const int* __restrict__ pM0, float4* __restrict__ epos,
    unsigned* __restrict__ notConv,
    const int* __restrict__ clearList, const int* __restrict__ pKc,
    float4* __restrict__ clearGrid,
    const int* __restrict__ mClrList, const int* __restrict__ pKm,
    unsigned* __restrict__ mClr, int lastStep) {
    __shared__ float4 sh[BLK];
    __shared__ unsigned sFlag;
    if (threadIdx.x == 0) sFlag = 0;
    __syncthreads();
    int K = *pK;
    int NC = (K + IPB - 1) / IPB;        // total conv chunks
    int BC = NC;
    if (BC > NF - 256) BC = NF - 256;    // always keep misc blocks
    const float t5[5] = {1.f, 2.f, 3.f, 2.f, 1.f};
    bool moved = false;

    if ((int)blockIdx.x < BC) {
        // ---------------- conv blocks ----------------
        int first, last, step;
        if (BC >= 64) {   // XCD-contiguous chunk ranges (measured neutral, kept)
            int xcd = blockIdx.x & 7, loc = blockIdx.x >> 3;
            int cpx = (NC + 7) >> 3;
            int bpx = ((BC - 1 - xcd) >> 3) + 1;
            first = xcd * cpx + loc;
            last = (xcd + 1) * cpx; if (last > NC) last = NC;
            step = bpx;
        } else {
            first = blockIdx.x; last = NC; step = BC;
        }
        for (int ib = first; ib < last; ib += step) {
            int li = threadIdx.x / 5;
            int dx = threadIdx.x % 5;
            int item = ib * IPB + li;
            float4 part = make_float4(0.f, 0.f, 0.f, 0.f);
            if (li < IPB && item < K) {
                int b = list[item];
                int bx = b / DIM2, rem = b % DIM2;
                int by = rem / DIM, bz = rem % DIM;
                int ix = bx + dx - 2;
                if ((unsigned)ix < (unsigned)DIM) {
                    float wx = t5[dx];
                    if (by >= 2 && by <= DIM - 3 && bz >= 2 && bz <= DIM - 3) {
                        #pragma unroll
                        for (int dy = 0; dy < 5; ++dy) {
                            float wxy = wx * t5[dy];
                            const float4* row = src + flatb(ix, by + dy - 2, bz - 2);
                            #pragma unroll
                            for (int dz = 0; dz < 5; ++dz) {
                                float w = wxy * t5[dz];
                                float4 e = row[dz];
                                part.x = fmaf(w, e.x, part.x);
                                part.y = fmaf(w, e.y, part.y);
                                part.z = fmaf(w, e.z, part.z);
                                part.w = fmaf(w, e.w, part.w);
                            }
                        }
                    } else {
                        for (int dy = 0; dy < 5; ++dy) {
                            int iy = by + dy - 2;
                            if ((unsigned)iy >= (unsigned)DIM) continue;
                            float wxy = wx * t5[dy];
                            for (int dz = 0; dz < 5; ++dz) {
                                int iz = bz + dz - 2;
                                if ((unsigned)iz >= (unsigned)DIM) continue;
                                float w = wxy * t5[dz];
                                float4 e = src[flatb(ix, iy, iz)];
                                part.x = fmaf(w, e.x, part.x);
                                part.y = fmaf(w, e.y, part.y);
                                part.z = fmaf(w, e.z, part.z);
                                part.w = fmaf(w, e.w, part.w);
                            }
                        }
                    }
                }
            }
            sh[threadIdx.x] = part;
            __syncthreads();
            if (threadIdx.x < 64) {
                // finalize by wave 0; head-flag segmented dedup on target bin
                int item2 = ib * IPB + threadIdx.x;
                bool valid = (threadIdx.x < IPB) && (item2 < K);
                int bn = -1;
                float4 sv = make_float4(0.f, 0.f, 0.f, 0.f);
                if (valid) {
                    int base5 = threadIdx.x * 5;
                    float4 a0 = sh[base5 + 0], a1 = sh[base5 + 1], a2 = sh[base5 + 2];
                    float4 a3 = sh[base5 + 3], a4 = sh[base5 + 4];
                    float sx = a0.x + a1.x + a2.x + a3.x + a4.x;
                    float sy = a0.y + a1.y + a2.y + a3.y + a4.y;
                    float sz = a0.z + a1.z + a2.z + a3.z + a4.z;
                    float sc = a0.w + a1.w + a2.w + a3.w + a4.w;
                    int b = list[item2];
                    float W = src[b].w;     // center count (occupied => sc>0)
                    float4 np = make_float4(sx / sc, sy / sc, sz / sc, W);
                    REo[item2] = np;
                    IDXo[b] = item2;
                    if (eposInit) eposInit[item2] = np;
                    if (!lastStep) {
                        bn = flatb(binf(np.x), binf(np.y), binf(np.z));
                        sv = make_float4(W * np.x, W * np.y, W * np.z, W);
                    }
                }
                if (!lastStep) {
                    // run heads: first lane or key differs from previous lane
                    int pbn = __shfl_up(bn, 1, 64);
                    unsigned f = (threadIdx.x == 0 || pbn != bn) ? 1u : 0u;
                    // leader = run end (next lane is a head, or last lane)
                    unsigned nf = __shfl_down(f, 1, 64);
                    bool leader = valid && (threadIdx.x == 63 || nf != 0u);
                    // flagged Hillis-Steele segmented inclusive sum
                    #pragma unroll
                    for (int off = 1; off < 64; off <<= 1) {
                        float ox = __shfl_up(sv.x, off, 64);
                        float oy = __shfl_up(sv.y, off, 64);
                        float oz = __shfl_up(sv.z, off, 64);
                        float ow = __shfl_up(sv.w, off, 64);
                        unsigned of = __shfl_up(f, off, 64);
                        if ((int)threadIdx.x >= off) {
                            if (!f) { sv.x += ox; sv.y += oy; sv.z += oz; sv.w += ow; }
                            f |= of;
                        }
                    }
                    bool fset = false;   // this lane's atomicOr set the bit first
                    if (leader) {
                        float* cell = (float*)&tgt[bn];
                        pk_add(cell + 0, sv.x, sv.y);
                        pk_add(cell + 2, sv.z, sv.w);
                        unsigned bit = 1u << (bn & 31);
                        unsigned old = atomicOr(&clT[(unsigned)bn >> 5], bit);
                        fset = (old & bit) == 0u;
                    }
                    // wave-aggregated append of first-set bins to next list
                    unsigned long long bal = __ballot(fset);
                    if (bal) {
                        int base = 0;
                        if (threadIdx.x == 0) base = atomicAdd(pKout, __popcll(bal));
                        base = __shfl(base, 0, 64);
                        if (fset)
                            listOut[base + __popcll(bal & ((1ull << threadIdx.x) - 1ull))] = bn;
                    }
                }
            }
            __syncthreads();    // sh reuse
        }
    } else {
        // ---------------- misc blocks ----------------
        int U = (updS > 0) ? (X ? n : *pM0) : 0;
        int CL = clearList ? *pKc : 0;
        int CM = mClrList ? *pKm : 0;
        int total = U + CL + CM;
        bool done = false;
        if (updS > 1) {
            for (int t = 1; t < updS; ++t) done |= (notConv[t] == 0u);
        }
        int stride = (NF - BC) * blockDim.x;
        for (int idx = (blockIdx.x - BC) * blockDim.x + threadIdx.x; idx < total;
             idx += stride) {
            if (idx < U) {
                int e = idx;
                if (X) {  // per-point step-1 convergence via PIdx
                    float x = X[3 * e + 0], y = X[3 * e + 1], z = X[3 * e + 2];
                    float4 rr = REp[PIdx[e]];
                    float ex = rr.x - x, ey = rr.y - y, ez = rr.z - z;
                    moved |= (fmaf(ex, ex, fmaf(ey, ey, ez * ez)) > TOL2);
                } else if (!done) {  // per-entry update to step-updS position
                    float4 p = epos[e];
                    int j = IDXp[flatb(binf(p.x), binf(p.y), binf(p.z))];
                    float4 rr = REp[j];
                    float ex = rr.x - p.x, ey = rr.y - p.y, ez = rr.z - p.z;
                    moved |= (fmaf(ex, ex, fmaf(ey, ey, ez * ez)) > TOL2);
                    epos[e] = make_float4(rr.x, rr.y, rr.z, p.w);
                }
            } else if (idx < U + CL) {
                clearGrid[clearList[idx - U]] = make_float4(0.f, 0.f, 0.f, 0.f);
            } else {
                int b = mClrList[idx - U - CL];
                mClr[(unsigned)b >> 5] = 0u;   // racing 0-stores are benign
            }
        }
    }
    if (moved) sFlag = 1;
    __syncthreads();
    if (threadIdx.x == 0 && updS > 0 && sFlag) notConv[updS] = 1u;
}

// ---- per-point output: gather epos via PIdx, optional last hop via REa/IDXa ----
__global__ void k_map(const int* __restrict__ PIdx, int n, const float4* __restrict__ epos,
                      const float4* __restrict__ REa, const int* __restrict__ IDXa,
                      const unsigned* __restrict__ notConv, float* __restrict__ out) {
    bool done = false;
    for (int t = 1; t <= 4; ++t) done |= (notConv[t] == 0u);
    int i = blockIdx.x * blockDim.x + threadIdx.x;
    if (i >= n) return;
    float4 p = epos[PIdx[i]];
    if (!done) {
        float4 rr = REa[IDXa[flatb(binf(p.x), binf(p.y), binf(p.z))]];
        p.x = rr.x; p.y = rr.y; p.z = rr.z;
    }
    out[3 * i + 0] = p.x;
    out[3 * i + 1] = p.y;
    out[3 * i + 2] = p.z;
}

extern "C" void kernel_launch(void* const* d_in, const int* in_sizes, int n_in,
                              void* d_out, int out_size, void* d_ws, size_t ws_size,
                              hipStream_t stream) {
    const float* X = (const float*)d_in[0];
    int n = in_sizes[0] / 3;

    char* ws = (char*)d_ws;
    int*      cnt     = (int*)ws;        // cnt[1..5] list sizes
    unsigned* notConv = (unsigned*)(ws + 32);
    size_t mB = (size_t)CLW * 4;
    size_t gB = (size_t)CELLS * 16;
    unsigned* m0 = (unsigned*)(ws + 256);
    unsigned* m1 = (unsigned*)(ws + 256 + mB);
    float4* A = (float4*)(ws + 256 + 2 * mB);
    float4* B = (float4*)((char*)A + gB);
    float4* C = (float4*)((char*)B + gB);
    int* IDXa = (int*)((char*)C + gB);
    int* IDXb = IDXa + CELLS;
    float4* REa  = (float4*)(IDXb + CELLS);
    float4* REb  = REa + n;
    float4* epos = REb + n;
    int* E0   = (int*)(epos + n);
    int* La   = E0 + n;
    int* Lb   = La + n;
    int* Lc   = Lb + n;
    int* Ld   = Lc + n;
    int* PIdx = Ld + n;
    float4* bucket = (float4*)(PIdx + n);
    int* blockHist = (int*)(bucket + n);
    int* regionPS  = blockHist + NB_A * NREG;

    // meta + masks only (A,B zeroed in histA, C in scatterA)
    hipMemsetAsync(ws, 0, 256 + 2 * mB, stream);

    k_histA<<<NB_A, BLK, 0, stream>>>(X, n, blockHist, A, B);
    k_colscan<<<NREG / BLK, BLK, 0, stream>>>(blockHist, regionPS);
    k_regprefix<<<1, 1024, 0, stream>>>(regionPS);
    k_scatterA<<<NB_A, BLK, 0, stream>>>(X, n, blockHist, regionPS, bucket, C);
    k_binB<<<NREG, BLK, 0, stream>>>(bucket, regionPS, A, E0, PIdx, &cnt[1]);

    // F1: conv A/E0 -> REa/IDXa (+epos init); scatter->B, set m0, append La
    k_fused<<<NF, BLK, 0, stream>>>(A, E0, &cnt[1], REa, IDXa, epos,
                                    B, m0, La, &cnt[2],
                                    0, nullptr, n, nullptr, nullptr, nullptr, nullptr,
                                    nullptr, notConv,
                                    nullptr, nullptr, nullptr,
                                    nullptr, nullptr, nullptr, 0);
    // F2: conv B/La -> REb/IDXb; scatter->C, set m1, append Lb; upd1 via PIdx
    //     (REa); clear grid A via E0; clear mask m0 via La
    k_fused<<<NF, BLK, 0, stream>>>(B, La, &cnt[2], REb, IDXb, nullptr,
                                    C, m1, Lb, &cnt[3],
                                    1, X, n, PIdx, REa, IDXa, &cnt[1], nullptr,
                                    notConv,
                                    E0, &cnt[1], A,
                                    La, &cnt[2], m0, 0);
    // F3: conv C/Lb -> REa/IDXa; scatter->A, set m0, append Lc; upd2 (REb/IDXb);
    //     clear grid B via La; clear mask m1 via Lb
    k_fused<<<NF, BLK, 0, stream>>>(C, Lb, &cnt[3], REa, IDXa, nullptr,
                                    A, m0, Lc, &cnt[4],
                                    2, nullptr, n, nullptr, REb, IDXb, &cnt[1], epos,
                                    notConv,
                                    La, &cnt[2], B,
                                    Lb, &cnt[3], m1, 0);
    // F4: conv A/Lc -> REb/IDXb; scatter->B, set m1, append Ld; upd3 (REa/IDXa)
    k_fused<<<NF, BLK, 0, stream>>>(A, Lc, &cnt[4], REb, IDXb, nullptr,
                                    B, m1, Ld, &cnt[5],
                                    3, nullptr, n, nullptr, REa, IDXa, &cnt[1], epos,
                                    notConv,
                                    nullptr, nullptr, nullptr,
                                    nullptr, nullptr, nullptr, 0);
    // F5: conv B/Ld -> REa/IDXa (conv only); upd4 (REb/IDXb)
    k_fused<<<NF, BLK, 0, stream>>>(B, Ld, &cnt[5], REa, IDXa, nullptr,
                                    nullptr, nullptr, nullptr, nullptr,
                                    4, nullptr, n, nullptr, REb, IDXb, &cnt[1], epos,
                                    notConv,
                                    nullptr, nullptr, nullptr,
                                    nullptr, nullptr, nullptr, 1);

    k_map<<<(n + BLK - 1) / BLK, BLK, 0, stream>>>(PIdx, n, epos, REa, IDXa,
                                                   notConv, (float*)d_out);
}

// Round 2
// 282.021 us; speedup vs baseline: 1.0285x; 1.0285x over previous
//
#include <hip/hip_runtime.h>

// MeanShift++ dense-grid, distinct-bin formulation, v14.
// v12 (246us) baseline + SEPARABLE CONV: [1,2,3,2,1]^3 = dense z-pass
// (src -> T1, fully coalesced streaming, 45MB) + sparse 25-tap (x,y) gather
// from T1 per occupied bin (was 125 taps). Grid rotation collapses to
// A<->B + fixed T1 (T1 never needs zeroing: dense overwrite), so workspace
// is unchanged (old C slot = T1). Misc work (upd/lazy grid clears) moved to
// z-pass tail blocks; conv kernel is pure conv+scatter.
// Dead levers (measured): unsorted direct-append list (v13, 290us: destroyed
// conv cache locality + dedup runs; sorted compactM list is load-bearing),
// region-LDS-tile conv (r11, -52%), flattened-tap 8-lane conv (r8, -78%),
// XCD chunk partition (r12, neutral; kept, harmless).
// k_fin remains folded into k_map (v13, harmless).

constexpr float BW   = 0.1f;
constexpr float TOL2 = 1e-6f;            // (1e-3)^2
constexpr int DIM  = 112, OFF = 56;      // bins in [-56,55]; |x|<5.6 covered
constexpr int DIM2 = DIM * DIM;
constexpr int CELLS = DIM * DIM * DIM;   // 1,404,928
constexpr int CLW = CELLS / 32;          // 43,904 mask words
constexpr int RDIM = 16, RC = 7;         // 16^3 regions of 7^3 cells
constexpr int NREG = RDIM * RDIM * RDIM; // 4096
constexpr int RC3 = RC * RC * RC;        // 343
constexpr int NB_A = 128, BLK = 256;
constexpr int NF = 2048;                 // fused-kernel grid
constexpr int IPB = 51;                  // conv items per block (51*5=255 thr)
constexpr int NZ4 = CELLS / 4;           // 4-cell z-windows (DIM%4==0)
constexpr int BCZ = NF - 256;            // dense z-pass blocks; 256 misc blocks
constexpr float FPS = 16777216.0f;       // 2^24 fixed-point scale
constexpr double FPSI = 1.0 / 16777216.0;

typedef float vf2 __attribute__((ext_vector_type(2)));

__device__ __forceinline__ int clampb(int v) { return v < 0 ? 0 : (v > DIM - 1 ? DIM - 1 : v); }
__device__ __forceinline__ int binf(float v) { return clampb((int)(v / BW) + OFF); }  // IEEE div+trunc == ref
__device__ __forceinline__ int flatb(int bx, int by, int bz) { return (bx * DIM + by) * DIM + bz; }
__device__ __forceinline__ int regOf(int bx, int by, int bz) {
    return ((bx / RC) * RDIM + (by / RC)) * RDIM + (bz / RC);
}
__device__ __forceinline__ int lcOf(int bx, int by, int bz) {
    return ((bx % RC) * RC + (by % RC)) * RC + (bz % RC);
}

__device__ __forceinline__ void pk_add(float* p, float a, float b) {
#if defined(__has_builtin) && __has_builtin(__builtin_amdgcn_global_atomic_fadd_v2f32)
    vf2 v = {a, b};
    __builtin_amdgcn_global_atomic_fadd_v2f32((vf2*)p, v);
#else
    atomicAdd(p, a);
    atomicAdd(p + 1, b);
#endif
}

// ---- pass A1: per-block region histogram (LDS) + streaming zero of grids A,B ----
__launch_bounds__(BLK)
__global__ void k_histA(const float* __restrict__ X, int n, int* __restrict__ blockHist,
                        float4* __restrict__ zeroA, float4* __restrict__ zeroB) {
    __shared__ int h[NREG];
    for (int i = threadIdx.x; i < NREG; i += blockDim.x) h[i] = 0;
    __syncthreads();
    int stride = gridDim.x * blockDim.x;
    for (int i = blockIdx.x * blockDim.x + threadIdx.x; i < n; i += stride) {
        float x = X[3 * i + 0], y = X[3 * i + 1], z = X[3 * i + 2];
        atomicAdd(&h[regOf(binf(x), binf(y), binf(z))], 1);
    }
    __syncthreads();
    for (int i = threadIdx.x; i < NREG; i += blockDim.x)
        blockHist[blockIdx.x * NREG + i] = h[i];
    for (int i = blockIdx.x * blockDim.x + threadIdx.x; i < CELLS; i += stride) {
        zeroA[i] = make_float4(0.f, 0.f, 0.f, 0.f);
        zeroB[i] = make_float4(0.f, 0.f, 0.f, 0.f);
    }
}

// ---- pass A2: per-region column scan over blocks ----
__global__ void k_colscan(int* __restrict__ blockHist, int* __restrict__ regionPS) {
    int r = blockIdx.x * blockDim.x + threadIdx.x;
    if (r >= NREG) return;
    int run = 0;
    for (int b = 0; b < NB_A; ++b) {
        int idx = b * NREG + r;
        int v = blockHist[idx];
        blockHist[idx] = run;
        run += v;
    }
    regionPS[r] = run;
}

// ---- pass A3: exclusive prefix over 4096 region totals ----
__launch_bounds__(1024)
__global__ void k_regprefix(int* __restrict__ regionPS) {
    __shared__ int buf[1024];
    int t = threadIdx.x;
    int v0 = regionPS[4 * t + 0], v1 = regionPS[4 * t + 1];
    int v2 = regionPS[4 * t + 2], v3 = regionPS[4 * t + 3];
    int s = v0 + v1 + v2 + v3;
    buf[t] = s;
    __syncthreads();
    for (int d = 1; d < 1024; d <<= 1) {
        int add = (t >= d) ? buf[t - d] : 0;
        __syncthreads();
        buf[t] += add;
        __syncthreads();
    }
    int excl = buf[t] - s;
    regionPS[4 * t + 0] = excl;
    regionPS[4 * t + 1] = excl + v0;
    regionPS[4 * t + 2] = excl + v0 + v1;
    regionPS[4 * t + 3] = excl + v0 + v1 + v2;
    if (t == 1023) regionPS[4096] = buf[1023];
}

// ---- pass A4: scatter points into region buckets ----
__launch_bounds__(BLK)
__global__ void k_scatterA(const float* __restrict__ X, int n,
                           const int* __restrict__ blockHist,
                           const int* __restrict__ regionPS,
                           float4* __restrict__ bucket) {
    __shared__ int cur[NREG];
    for (int i = threadIdx.x; i < NREG; i += blockDim.x) cur[i] = 0;
    __syncthreads();
    int stride = gridDim.x * blockDim.x;
    for (int i = blockIdx.x * blockDim.x + threadIdx.x; i < n; i += stride) {
        float x = X[3 * i + 0], y = X[3 * i + 1], z = X[3 * i + 2];
        int r = regOf(binf(x), binf(y), binf(z));
        int pos = regionPS[r] + blockHist[blockIdx.x * NREG + r] + atomicAdd(&cur[r], 1);
        bucket[pos] = make_float4(x, y, z, __int_as_float(i));
    }
}

// ---- pass B: one block/region — LDS int-atomic accumulate, compact, PIdx ----
__launch_bounds__(BLK)
__global__ void k_binB(const float4* __restrict__ bucket, const int* __restrict__ regionPS,
                       float4* __restrict__ A, int* __restrict__ E0,
                       int* __restrict__ PIdx, int* __restrict__ gM0) {
    __shared__ unsigned long long aX[RC3], aY[RC3], aZ[RC3];
    __shared__ unsigned aC[RC3];
    __shared__ int cidx[RC3];
    __shared__ int cnt, cur, sBase;
    int r = blockIdx.x;
    for (int c = threadIdx.x; c < RC3; c += blockDim.x) {
        aX[c] = 0ull; aY[c] = 0ull; aZ[c] = 0ull; aC[c] = 0u;
    }
    if (threadIdx.x == 0) { cnt = 0; cur = 0; }
    __syncthreads();
    int start = regionPS[r], end = regionPS[r + 1];
    for (int i = start + threadIdx.x; i < end; i += blockDim.x) {
        float4 p = bucket[i];
        int lc = lcOf(binf(p.x), binf(p.y), binf(p.z));
        atomicAdd(&aX[lc], (unsigned long long)(long long)rintf(p.x * FPS));
        atomicAdd(&aY[lc], (unsigned long long)(long long)rintf(p.y * FPS));
        atomicAdd(&aZ[lc], (unsigned long long)(long long)rintf(p.z * FPS));
        atomicAdd(&aC[lc], 1u);
    }
    __syncthreads();
    int myc = 0;
    for (int c = threadIdx.x; c < RC3; c += blockDim.x)
        if (aC[c] > 0u) ++myc;
    if (myc) atomicAdd(&cnt, myc);
    __syncthreads();
    if (threadIdx.x == 0 && cnt > 0) sBase = atomicAdd(gM0, cnt);
    __syncthreads();
    int rx = r / (RDIM * RDIM), ry = (r / RDIM) % RDIM, rz = r % RDIM;
    for (int c = threadIdx.x; c < RC3; c += blockDim.x) {
        if (aC[c] > 0u) {
            int idx = sBase + atomicAdd(&cur, 1);
            cidx[c] = idx;
            int bx = rx * RC + c / (RC * RC);
            int by = ry * RC + (c / RC) % RC;
            int bz = rz * RC + c % RC;
            int b = flatb(bx, by, bz);
            E0[idx] = b;
            A[b] = make_float4((float)((double)(long long)aX[c] * FPSI),
                               (float)((double)(long long)aY[c] * FPSI),
                               (float)((double)(long long)aZ[c] * FPSI),
                               (float)aC[c]);
        }
    }
    __syncthreads();
    for (int i = start + threadIdx.x; i < end; i += blockDim.x) {
        float4 p = bucket[i];
        int lc = lcOf(binf(p.x), binf(p.y), binf(p.z));
        PIdx[__float_as_int(p.w)] = cidx[lc];
    }
}

// ---- per-step kernel 1: dense z-conv src -> T1, plus misc tail blocks ----
// Blocks [0, BCZ): each thread computes a 4-cell z-window (DIM%4==0, windows
//   never cross a z-row). T1(x,y,z) = sum_dz t5[dz] src(x,y,z+dz-2), zero-pad.
// Blocks [BCZ, NF): grid-stride misc: convergence update for step updS and
//   lazy clear of the grid that will be the next scatter target.
__launch_bounds__(BLK)
__global__ void k_zconv(const float4* __restrict__ src, float4* __restrict__ T1,
                        int updS, const float* __restrict__ X, int n,
                        const int* __restrict__ PIdx,
                        const float4* __restrict__ REp, const int* __restrict__ IDXp,
                        const int* __restrict__ pM0, float4* __restrict__ epos,
                        unsigned* __restrict__ notConv,
                        const int* __restrict__ clearList, const int* __restrict__ pKc,
                        float4* __restrict__ clearGrid) {
    __shared__ unsigned sFlag;
    if (threadIdx.x == 0) sFlag = 0;
    __syncthreads();
    bool moved = false;
    if ((int)blockIdx.x < BCZ) {
        for (int w = blockIdx.x * BLK + threadIdx.x; w < NZ4; w += BCZ * BLK) {
            int c0 = w * 4;
            int z0 = c0 % DIM;
            float4 e[8];
            #pragma unroll
            for (int k = 0; k < 8; ++k) {
                int z = z0 + k - 2;
                if ((unsigned)z < (unsigned)DIM) e[k] = src[c0 + k - 2];
                else e[k] = make_float4(0.f, 0.f, 0.f, 0.f);
            }
            #pragma unroll
            for (int j = 0; j < 4; ++j) {
                float4 r;
                r.x = e[j].x + e[j + 4].x + 2.f * (e[j + 1].x + e[j + 3].x) + 3.f * e[j + 2].x;
                r.y = e[j].y + e[j + 4].y + 2.f * (e[j + 1].y + e[j + 3].y) + 3.f * e[j + 2].y;
                r.z = e[j].z + e[j + 4].z + 2.f * (e[j + 1].z + e[j + 3].z) + 3.f * e[j + 2].z;
                r.w = e[j].w + e[j + 4].w + 2.f * (e[j + 1].w + e[j + 3].w) + 3.f * e[j + 2].w;
                T1[c0 + j] = r;
            }
        }
    } else {
        int U = (updS > 0) ? (X ? n : *pM0) : 0;
        int CL = clearList ? *pKc : 0;
        int total = U + CL;
        bool done = false;
        if (updS > 1) {
            for (int t = 1; t < updS; ++t) done |= (notConv[t] == 0u);
        }
        int stride = (NF - BCZ) * BLK;
        for (int idx = (blockIdx.x - BCZ) * BLK + threadIdx.x; idx < total;
             idx += stride) {
            if (idx < U) {
                int e = idx;
                if (X) {  // per-point step-1 convergence via PIdx
                    float x = X[3 * e + 0], y = X[3 * e + 1], z = X[3 * e + 2];
                    float4 rr = REp[PIdx[e]];
                    float ex = rr.x - x, ey = rr.y - y, ez = rr.z - z;
                    moved |= (fmaf(ex, ex, fmaf(ey, ey, ez * ez)) > TOL2);
                } else if (!done) {  // per-entry update to step-updS position
                    float4 p = epos[e];
                    int j = IDXp[flatb(binf(p.x), binf(p.y), binf(p.z))];
                    float4 rr = REp[j];
                    float ex = rr.x - p.x, ey = rr.y - p.y, ez = rr.z - p.z;
                    moved |= (fmaf(ex, ex, fmaf(ey, ey, ez * ez)) > TOL2);
                    epos[e] = make_float4(rr.x, rr.y, rr.z, p.w);
                }
            } else {
                clearGrid[clearList[idx - U]] = make_float4(0.f, 0.f, 0.f, 0.f);
            }
        }
    }
    if (moved) sFlag = 1;
    __syncthreads();
    if (threadIdx.x == 0 && updS > 0 && sFlag) notConv[updS] = 1u;
}

// ---- per-step kernel 2: 25-tap (x,y) conv from T1 at occupied bins ----
// 51 items/chunk, 5 threads/item (one dx each, 5 dy taps), LDS reduce;
// finalize by wave 0 with head-flag segmented dedup (sorted list => adjacent
// equal targets merge; leaders issue pk_add/atomicOr).
__launch_bounds__(BLK)
__global__ void k_conv(const float4* __restrict__ T1, const float4* __restrict__ src,
                       const int* __restrict__ list, const int* __restrict__ pK,
                       float4* __restrict__ REo, int* __restrict__ IDXo,
                       float4* __restrict__ eposInit,
                       float4* __restrict__ tgt, unsigned* __restrict__ clT,
                       int lastStep) {
    __shared__ float4 sh[BLK];
    int K = *pK;
    int NC = (K + IPB - 1) / IPB;        // total conv chunks
    int BC = NC > NF ? NF : NC;          // live blocks
    if ((int)blockIdx.x >= BC) return;
    const float t5[5] = {1.f, 2.f, 3.f, 2.f, 1.f};

    int first, last, step;
    if (BC >= 64) {   // XCD-contiguous chunk ranges (measured neutral, kept)
        int xcd = blockIdx.x & 7, loc = blockIdx.x >> 3;
        int cpx = (NC + 7) >> 3;
        int bpx = ((BC - 1 - xcd) >> 3) + 1;
        first = xcd * cpx + loc;
        last = (xcd + 1) * cpx; if (last > NC) last = NC;
        step = bpx;
    } else {
        first = blockIdx.x; last = NC; step = BC;
    }
    for (int ib = first; ib < last; ib += step) {
        int li = threadIdx.x / 5;
        int dx = threadIdx.x % 5;
        int item = ib * IPB + li;
        float4 part = make_float4(0.f, 0.f, 0.f, 0.f);
        if (li < IPB && item < K) {
            int b = list[item];
            int bx = b / DIM2, rem = b % DIM2;
            int by = rem / DIM, bz = rem % DIM;
            int ix = bx + dx - 2;
            if ((unsigned)ix < (unsigned)DIM) {
                float wx = t5[dx];
                if (by >= 2 && by <= DIM - 3) {
                    const float4* col = T1 + flatb(ix, by - 2, bz);
                    #pragma unroll
                    for (int dy = 0; dy < 5; ++dy) {
                        float w = wx * t5[dy];
                        float4 e = col[dy * DIM];
                        part.x = fmaf(w, e.x, part.x);
                        part.y = fmaf(w, e.y, part.y);
                        part.z = fmaf(w, e.z, part.z);
                        part.w = fmaf(w, e.w, part.w);
                    }
                } else {
                    for (int dy = 0; dy < 5; ++dy) {
                        int iy = by + dy - 2;
                        if ((unsigned)iy >= (unsigned)DIM) continue;
                        float w = wx * t5[dy];
                        float4 e = T1[flatb(ix, iy, bz)];
                        part.x = fmaf(w, e.x, part.x);
                        part.y = fmaf(w, e.y, part.y);
                        part.z = fmaf(w, e.z, part.z);
                        part.w = fmaf(w, e.w, part.w);
                    }
                }
            }
        }
        sh[threadIdx.x] = part;
        __syncthreads();
        if (threadIdx.x < 64) {
            // finalize by wave 0; head-flag segmented dedup on target bin
            int item2 = ib * IPB + threadIdx.x;
            bool valid = (threadIdx.x < IPB) && (item2 < K);
            int bn = -1;
            float4 sv = make_float4(0.f, 0.f, 0.f, 0.f);
            if (valid) {
                int base5 = threadIdx.x * 5;
                float4 a0 = sh[base5 + 0], a1 = sh[base5 + 1], a2 = sh[base5 + 2];
                float4 a3 = sh[base5 + 3], a4 = sh[base5 + 4];
                float sx = a0.x + a1.x + a2.x + a3.x + a4.x;
                float sy = a0.y + a1.y + a2.y + a3.y + a4.y;
                float sz = a0.z + a1.z + a2.z + a3.z + a4.z;
                float sc = a0.w + a1.w + a2.w + a3.w + a4.w;
                int b = list[item2];
                float W = src[b].w;     // center count (occupied => sc>0)
                float4 np = make_float4(sx / sc, sy / sc, sz / sc, W);
                REo[item2] = np;
                IDXo[b] = item2;
                if (eposInit) eposInit[item2] = np;
                if (!lastStep) {
                    bn = flatb(binf(np.x), binf(np.y), binf(np.z));
                    sv = make_float4(W * np.x, W * np.y, W * np.z, W);
                }
            }
            if (!lastStep) {
                // run heads: first lane or key differs from previous lane
                int pbn = __shfl_up(bn, 1, 64);
                unsigned f = (threadIdx.x == 0 || pbn != bn) ? 1u : 0u;
                // leader = run end (next lane is a head, or last lane)
                unsigned nf = __shfl_down(f, 1, 64);
                bool leader = valid && (threadIdx.x == 63 || nf != 0u);
                // flagged Hillis-Steele segmented inclusive sum
                #pragma unroll
                for (int off = 1; off < 64; off <<= 1) {
                    float ox = __shfl_up(sv.x, off, 64);
                    float oy = __shfl_up(sv.y, off, 64);
                    float oz = __shfl_up(sv.z, off, 64);
                    float ow = __shfl_up(sv.w, off, 64);
                    unsigned of = __shfl_up(f, off, 64);
                    if ((int)threadIdx.x >= off) {
                        if (!f) { sv.x += ox; sv.y += oy; sv.z += oz; sv.w += ow; }
                        f |= of;
                    }
                }
                if (leader) {
                    float* cell = (float*)&tgt[bn];
                    pk_add(cell + 0, sv.x, sv.y);
                    pk_add(cell + 2, sv.z, sv.w);
                    atomicOr(&clT[(unsigned)bn >> 5], 1u << (bn & 31));
                }
            }
        }
        __syncthreads();    // sh reuse
    }
}

// ---- mask -> bin-sorted list (block scan, 1 atomic/block), clears mask ----
__launch_bounds__(BLK)
__global__ void k_compactM(unsigned* __restrict__ mask, int* __restrict__ listOut,
                           int* __restrict__ pKout) {
    __shared__ int scan[BLK];
    __shared__ int sBase;
    int i = blockIdx.x * blockDim.x + threadIdx.x;
    unsigned w = (i < CLW) ? mask[i] : 0u;
    if (i < CLW && w) mask[i] = 0u;
    int c = __popc(w);
    scan[threadIdx.x] = c;
    __syncthreads();
    for (int d = 1; d < BLK; d <<= 1) {
        int add = (threadIdx.x >= (unsigned)d) ? scan[threadIdx.x - d] : 0;
        __syncthreads();
        scan[threadIdx.x] += add;
        __syncthreads();
    }
    if (threadIdx.x == BLK - 1) {
        int tot = scan[BLK - 1];
        sBase = tot ? atomicAdd(pKout, tot) : 0;
    }
    __syncthreads();
    int base = sBase + scan[threadIdx.x] - c;
    int bb = i * 32;
    while (w) {
        int b = __ffs(w) - 1;
        listOut[base++] = bb + b;
        w &= w - 1;
    }
}

// ---- per-point output: gather epos via PIdx, optional last hop via REa/IDXa ----
__global__ void k_map(const int* __restrict__ PIdx, int n, const float4* __restrict__ epos,
                      const float4* __restrict__ REa, const int* __restrict__ IDXa,
                      const unsigned* __restrict__ notConv, float* __restrict__ out) {
    bool done = false;
    for (int t = 1; t <= 4; ++t) done |= (notConv[t] == 0u);
    int i = blockIdx.x * blockDim.x + threadIdx.x;
    if (i >= n) return;
    float4 p = epos[PIdx[i]];
    if (!done) {
        float4 rr = REa[IDXa[flatb(binf(p.x), binf(p.y), binf(p.z))]];
        p.x = rr.x; p.y = rr.y; p.z = rr.z;
    }
    out[3 * i + 0] = p.x;
    out[3 * i + 1] = p.y;
    out[3 * i + 2] = p.z;
}

extern "C" void kernel_launch(void* const* d_in, const int* in_sizes, int n_in,
                              void* d_out, int out_size, void* d_ws, size_t ws_size,
                              hipStream_t stream) {
    const float* X = (const float*)d_in[0];
    int n = in_sizes[0] / 3;

    char* ws = (char*)d_ws;
    int*      cnt     = (int*)ws;        // cnt[1..5] list sizes
    unsigned* notConv = (unsigned*)(ws + 32);
    size_t mB = (size_t)CLW * 4;
    size_t gB = (size_t)CELLS * 16;
    unsigned* m0 = (unsigned*)(ws + 256);
    unsigned* m1 = (unsigned*)(ws + 256 + mB);
    float4* A  = (float4*)(ws + 256 + 2 * mB);
    float4* B  = (float4*)((char*)A + gB);
    float4* T1 = (float4*)((char*)B + gB);    // separable-conv temp (old C slot)
    int* IDXa = (int*)((char*)T1 + gB);
    int* IDXb = IDXa + CELLS;
    float4* REa  = (float4*)(IDXb + CELLS);
    float4* REb  = REa + n;
    float4* epos = REb + n;
    int* E0   = (int*)(epos + n);
    int* La   = E0 + n;
    int* Lb   = La + n;
    int* Lc   = Lb + n;
    int* Ld   = Lc + n;
    int* PIdx = Ld + n;
    float4* bucket = (float4*)(PIdx + n);
    int* blockHist = (int*)(bucket + n);
    int* regionPS  = blockHist + NB_A * NREG;

    // meta + masks only (A,B zeroed in histA; T1 is always densely overwritten)
    hipMemsetAsync(ws, 0, 256 + 2 * mB, stream);

    const int NCM = (CLW + BLK - 1) / BLK;   // compactM blocks

    k_histA<<<NB_A, BLK, 0, stream>>>(X, n, blockHist, A, B);
    k_colscan<<<NREG / BLK, BLK, 0, stream>>>(blockHist, regionPS);
    k_regprefix<<<1, 1024, 0, stream>>>(regionPS);
    k_scatterA<<<NB_A, BLK, 0, stream>>>(X, n, blockHist, regionPS, bucket);
    k_binB<<<NREG, BLK, 0, stream>>>(bucket, regionPS, A, E0, PIdx, &cnt[1]);

    // step 1: z-pass A->T1; conv T1/E0 -> REa/IDXa (+epos init); scatter->B+m0
    k_zconv<<<NF, BLK, 0, stream>>>(A, T1, 0, nullptr, n, nullptr, nullptr, nullptr,
                                    nullptr, nullptr, notConv, nullptr, nullptr, nullptr);
    k_conv<<<NF, BLK, 0, stream>>>(T1, A, E0, &cnt[1], REa, IDXa, epos, B, m0, 0);
    k_compactM<<<NCM, BLK, 0, stream>>>(m0, La, &cnt[2]);

    // step 2: z-pass B->T1 (+upd1 via X/PIdx/REa, clear A via E0);
    //         conv T1/La -> REb/IDXb; scatter->A+m1
    k_zconv<<<NF, BLK, 0, stream>>>(B, T1, 1, X, n, PIdx, REa, IDXa, &cnt[1],
                                    nullptr, notConv, E0, &cnt[1], A);
    k_conv<<<NF, BLK, 0, stream>>>(T1, B, La, &cnt[2], REb, IDXb, nullptr, A, m1, 0);
    k_compactM<<<NCM, BLK, 0, stream>>>(m1, Lb, &cnt[3]);

    // step 3: z-pass A->T1 (+upd2 epos/REb/IDXb, clear B via La);
    //         conv T1/Lb -> REa/IDXa; scatter->B+m0
    k_zconv<<<NF, BLK, 0, stream>>>(A, T1, 2, nullptr, n, nullptr, REb, IDXb, &cnt[1],
                                    epos, notConv, La, &cnt[2], B);
    k_conv<<<NF, BLK, 0, stream>>>(T1, A, Lb, &cnt[3], REa, IDXa, nullptr, B, m0, 0);
    k_compactM<<<NCM, BLK, 0, stream>>>(m0, Lc, &cnt[4]);

    // step 4: z-pass B->T1 (+upd3 epos/REa/IDXa, clear A via Lb);
    //         conv T1/Lc -> REb/IDXb; scatter->A+m1
    k_zconv<<<NF, BLK, 0, stream>>>(B, T1, 3, nullptr, n, nullptr, REa, IDXa, &cnt[1],
                                    epos, notConv, Lb, &cnt[3], A);
    k_conv<<<NF, BLK, 0, stream>>>(T1, B, Lc, &cnt[4], REb, IDXb, nullptr, A, m1, 0);
    k_compactM<<<NCM, BLK, 0, stream>>>(m1, Ld, &cnt[5]);

    // step 5 (last): z-pass A->T1 (+upd4 epos/REb/IDXb); conv only
    k_zconv<<<NF, BLK, 0, stream>>>(A, T1, 4, nullptr, n, nullptr, REb, IDXb, &cnt[1],
                                    epos, notConv, nullptr, nullptr, nullptr);
    k_conv<<<NF, BLK, 0, stream>>>(T1, A, Ld, &cnt[5], REa, IDXa, nullptr,
                                   nullptr, nullptr, 1);

    k_map<<<(n + BLK - 1) / BLK, BLK, 0, stream>>>(PIdx, n, epos, REa, IDXa,
                                                   notConv, (float*)d_out);
}

// Round 3
// 260.417 us; speedup vs baseline: 1.1138x; 1.0830x over previous
//
#include <hip/hip_runtime.h>

// MeanShift++ dense-grid, distinct-bin formulation, v15.
// = v12 (246us, best) + 4-WAVE-PARALLEL FINALIZE: the per-chunk finalize
// (np compute, RE/IDX writes, target-bin segmented dedup, scattered atomics)
// was wave-0-only (51 lanes active, 192 threads idle, 6 scan rounds); now
// split 13/13/13/12 across all 4 waves (4 scan rounds, 4x outstanding
// scattered ops). Runs split at wave boundaries issue separate atomics
// (correct: each item in exactly one leader's sum). Plus: plain-load test
// of the mask word before atomicOr (skips RMW on already-set hot words).
// k_fin stays folded into k_map (v13, harmless).
// Dead levers (measured): separable z-pass conv (v14, +36us: conv is NOT
// tap-bound, dense pass pure overhead), unsorted direct-append list (v13,
// +44us: sorted compactM list is load-bearing for locality+dedup),
// region-LDS-tile conv (r11, -52%), flattened-tap 8-lane conv (r8, -78%),
// XCD chunk partition (r12, neutral; kept, harmless).

constexpr float BW   = 0.1f;
constexpr float TOL2 = 1e-6f;            // (1e-3)^2
constexpr int DIM  = 112, OFF = 56;      // bins in [-56,55]; |x|<5.6 covered
constexpr int DIM2 = DIM * DIM;
constexpr int CELLS = DIM * DIM * DIM;   // 1,404,928
constexpr int CLW = CELLS / 32;          // 43,904 mask words
constexpr int RDIM = 16, RC = 7;         // 16^3 regions of 7^3 cells
constexpr int NREG = RDIM * RDIM * RDIM; // 4096
constexpr int RC3 = RC * RC * RC;        // 343
constexpr int NB_A = 128, BLK = 256;
constexpr int NF = 2048;                 // k_fused grid
constexpr int IPB = 51;                  // conv items per block (51*5=255 thr)
constexpr float FPS = 16777216.0f;       // 2^24 fixed-point scale
constexpr double FPSI = 1.0 / 16777216.0;

typedef float vf2 __attribute__((ext_vector_type(2)));

__device__ __forceinline__ int clampb(int v) { return v < 0 ? 0 : (v > DIM - 1 ? DIM - 1 : v); }
__device__ __forceinline__ int binf(float v) { return clampb((int)(v / BW) + OFF); }  // IEEE div+trunc == ref
__device__ __forceinline__ int flatb(int bx, int by, int bz) { return (bx * DIM + by) * DIM + bz; }
__device__ __forceinline__ int regOf(int bx, int by, int bz) {
    return ((bx / RC) * RDIM + (by / RC)) * RDIM + (bz / RC);
}
__device__ __forceinline__ int lcOf(int bx, int by, int bz) {
    return ((bx % RC) * RC + (by % RC)) * RC + (bz % RC);
}

__device__ __forceinline__ void pk_add(float* p, float a, float b) {
#if defined(__has_builtin) && __has_builtin(__builtin_amdgcn_global_atomic_fadd_v2f32)
    vf2 v = {a, b};
    __builtin_amdgcn_global_atomic_fadd_v2f32((vf2*)p, v);
#else
    atomicAdd(p, a);
    atomicAdd(p + 1, b);
#endif
}

// ---- pass A1: per-block region histogram (LDS) + streaming zero of grids A,B ----
__launch_bounds__(BLK)
__global__ void k_histA(const float* __restrict__ X, int n, int* __restrict__ blockHist,
                        float4* __restrict__ zeroA, float4* __restrict__ zeroB) {
    __shared__ int h[NREG];
    for (int i = threadIdx.x; i < NREG; i += blockDim.x) h[i] = 0;
    __syncthreads();
    int stride = gridDim.x * blockDim.x;
    for (int i = blockIdx.x * blockDim.x + threadIdx.x; i < n; i += stride) {
        float x = X[3 * i + 0], y = X[3 * i + 1], z = X[3 * i + 2];
        atomicAdd(&h[regOf(binf(x), binf(y), binf(z))], 1);
    }
    __syncthreads();
    for (int i = threadIdx.x; i < NREG; i += blockDim.x)
        blockHist[blockIdx.x * NREG + i] = h[i];
    for (int i = blockIdx.x * blockDim.x + threadIdx.x; i < CELLS; i += stride) {
        zeroA[i] = make_float4(0.f, 0.f, 0.f, 0.f);
        zeroB[i] = make_float4(0.f, 0.f, 0.f, 0.f);
    }
}

// ---- pass A2: per-region column scan over blocks ----
__global__ void k_colscan(int* __restrict__ blockHist, int* __restrict__ regionPS) {
    int r = blockIdx.x * blockDim.x + threadIdx.x;
    if (r >= NREG) return;
    int run = 0;
    for (int b = 0; b < NB_A; ++b) {
        int idx = b * NREG + r;
        int v = blockHist[idx];
        blockHist[idx] = run;
        run += v;
    }
    regionPS[r] = run;
}

// ---- pass A3: exclusive prefix over 4096 region totals ----
__launch_bounds__(1024)
__global__ void k_regprefix(int* __restrict__ regionPS) {
    __shared__ int buf[1024];
    int t = threadIdx.x;
    int v0 = regionPS[4 * t + 0], v1 = regionPS[4 * t + 1];
    int v2 = regionPS[4 * t + 2], v3 = regionPS[4 * t + 3];
    int s = v0 + v1 + v2 + v3;
    buf[t] = s;
    __syncthreads();
    for (int d = 1; d < 1024; d <<= 1) {
        int add = (t >= d) ? buf[t - d] : 0;
        __syncthreads();
        buf[t] += add;
        __syncthreads();
    }
    int excl = buf[t] - s;
    regionPS[4 * t + 0] = excl;
    regionPS[4 * t + 1] = excl + v0;
    regionPS[4 * t + 2] = excl + v0 + v1;
    regionPS[4 * t + 3] = excl + v0 + v1 + v2;
    if (t == 1023) regionPS[4096] = buf[1023];
}

// ---- pass A4: scatter points into region buckets + streaming zero of grid C ----
__launch_bounds__(BLK)
__global__ void k_scatterA(const float* __restrict__ X, int n,
                           const int* __restrict__ blockHist,
                           const int* __restrict__ regionPS,
                           float4* __restrict__ bucket, float4* __restrict__ zeroC) {
    __shared__ int cur[NREG];
    for (int i = threadIdx.x; i < NREG; i += blockDim.x) cur[i] = 0;
    __syncthreads();
    int stride = gridDim.x * blockDim.x;
    for (int i = blockIdx.x * blockDim.x + threadIdx.x; i < n; i += stride) {
        float x = X[3 * i + 0], y = X[3 * i + 1], z = X[3 * i + 2];
        int r = regOf(binf(x), binf(y), binf(z));
        int pos = regionPS[r] + blockHist[blockIdx.x * NREG + r] + atomicAdd(&cur[r], 1);
        bucket[pos] = make_float4(x, y, z, __int_as_float(i));
    }
    for (int i = blockIdx.x * blockDim.x + threadIdx.x; i < CELLS; i += stride)
        zeroC[i] = make_float4(0.f, 0.f, 0.f, 0.f);
}

// ---- pass B: one block/region — LDS int-atomic accumulate, compact, PIdx ----
__launch_bounds__(BLK)
__global__ void k_binB(const float4* __restrict__ bucket, const int* __restrict__ regionPS,
                       float4* __restrict__ A, int* __restrict__ E0,
                       int* __restrict__ PIdx, int* __restrict__ gM0) {
    __shared__ unsigned long long aX[RC3], aY[RC3], aZ[RC3];
    __shared__ unsigned aC[RC3];
    __shared__ int cidx[RC3];
    __shared__ int cnt, cur, sBase;
    int r = blockIdx.x;
    for (int c = threadIdx.x; c < RC3; c += blockDim.x) {
        aX[c] = 0ull; aY[c] = 0ull; aZ[c] = 0ull; aC[c] = 0u;
    }
    if (threadIdx.x == 0) { cnt = 0; cur = 0; }
    __syncthreads();
    int start = regionPS[r], end = regionPS[r + 1];
    for (int i = start + threadIdx.x; i < end; i += blockDim.x) {
        float4 p = bucket[i];
        int lc = lcOf(binf(p.x), binf(p.y), binf(p.z));
        atomicAdd(&aX[lc], (unsigned long long)(long long)rintf(p.x * FPS));
        atomicAdd(&aY[lc], (unsigned long long)(long long)rintf(p.y * FPS));
        atomicAdd(&aZ[lc], (unsigned long long)(long long)rintf(p.z * FPS));
        atomicAdd(&aC[lc], 1u);
    }
    __syncthreads();
    int myc = 0;
    for (int c = threadIdx.x; c < RC3; c += blockDim.x)
        if (aC[c] > 0u) ++myc;
    if (myc) atomicAdd(&cnt, myc);
    __syncthreads();
    if (threadIdx.x == 0 && cnt > 0) sBase = atomicAdd(gM0, cnt);
    __syncthreads();
    int rx = r / (RDIM * RDIM), ry = (r / RDIM) % RDIM, rz = r % RDIM;
    for (int c = threadIdx.x; c < RC3; c += blockDim.x) {
        if (aC[c] > 0u) {
            int idx = sBase + atomicAdd(&cur, 1);
            cidx[c] = idx;
            int bx = rx * RC + c / (RC * RC);
            int by = ry * RC + (c / RC) % RC;
            int bz = rz * RC + c % RC;
            int b = flatb(bx, by, bz);
            E0[idx] = b;
            A[b] = make_float4((float)((double)(long long)aX[c] * FPSI),
                               (float)((double)(long long)aY[c] * FPSI),
                               (float)((double)(long long)aZ[c] * FPSI),
                               (float)aC[c]);
        }
    }
    __syncthreads();
    for (int i = start + threadIdx.x; i < end; i += blockDim.x) {
        float4 p = bucket[i];
        int lc = lcOf(binf(p.x), binf(p.y), binf(p.z));
        PIdx[__float_as_int(p.w)] = cidx[lc];
    }
}

// ---- fused per-step kernel ----
// Blocks [0, BC): conv, 51 items/chunk, 5 threads/item (one dx-plane each),
//   row-contiguous taps, LDS reduce; finalize split 13/13/13/12 across the
//   4 waves (per-wave head-flag segmented dedup; leaders issue atomics;
//   wave-boundary run splits just issue extra atomics — correct).
// Blocks [BC, NF): grid-stride misc (upd / targeted clear).
__launch_bounds__(BLK)
__global__ void k_fused(
    const float4* __restrict__ src, const int* __restrict__ list, const int* __restrict__ pK,
    float4* __restrict__ REo, int* __restrict__ IDXo, float4* __restrict__ eposInit,
    float4* __restrict__ tgt, unsigned* __restrict__ clT,
    int updS, const float* __restrict__ X, int n, const int* __restrict__ PIdx,
    const float4* __restrict__ REp, const int* __restrict__ IDXp,
    const int* __restrict__ pM0, float4* __restrict__ epos,
    unsigned* __restrict__ notConv,
    const int* __restrict__ clearList, const int* __restrict__ pKc,
    float4* __restrict__ clearGrid, int lastStep) {
    __shared__ float4 sh[BLK];
    __shared__ unsigned sFlag;
    if (threadIdx.x == 0) sFlag = 0;
    __syncthreads();
    int K = *pK;
    int NC = (K + IPB - 1) / IPB;        // total conv chunks
    int BC = NC;
    if (BC > NF - 256) BC = NF - 256;    // always keep misc blocks
    const float t5[5] = {1.f, 2.f, 3.f, 2.f, 1.f};
    bool moved = false;

    if ((int)blockIdx.x < BC) {
        // ---------------- conv blocks ----------------
        int first, last, step;
        if (BC >= 64) {   // XCD-contiguous chunk ranges (measured neutral, kept)
            int xcd = blockIdx.x & 7, loc = blockIdx.x >> 3;
            int cpx = (NC + 7) >> 3;
            int bpx = ((BC - 1 - xcd) >> 3) + 1;
            first = xcd * cpx + loc;
            last = (xcd + 1) * cpx; if (last > NC) last = NC;
            step = bpx;
        } else {
            first = blockIdx.x; last = NC; step = BC;
        }
        for (int ib = first; ib < last; ib += step) {
            int li = threadIdx.x / 5;
            int dx = threadIdx.x % 5;
            int item = ib * IPB + li;
            float4 part = make_float4(0.f, 0.f, 0.f, 0.f);
            if (li < IPB && item < K) {
                int b = list[item];
                int bx = b / DIM2, rem = b % DIM2;
                int by = rem / DIM, bz = rem % DIM;
                int ix = bx + dx - 2;
                if ((unsigned)ix < (unsigned)DIM) {
                    float wx = t5[dx];
                    if (by >= 2 && by <= DIM - 3 && bz >= 2 && bz <= DIM - 3) {
                        #pragma unroll
                        for (int dy = 0; dy < 5; ++dy) {
                            float wxy = wx * t5[dy];
                            const float4* row = src + flatb(ix, by + dy - 2, bz - 2);
                            #pragma unroll
                            for (int dz = 0; dz < 5; ++dz) {
                                float w = wxy * t5[dz];
                                float4 e = row[dz];
                                part.x = fmaf(w, e.x, part.x);
                                part.y = fmaf(w, e.y, part.y);
                                part.z = fmaf(w, e.z, part.z);
                                part.w = fmaf(w, e.w, part.w);
                            }
                        }
                    } else {
                        for (int dy = 0; dy < 5; ++dy) {
                            int iy = by + dy - 2;
                            if ((unsigned)iy >= (unsigned)DIM) continue;
                            float wxy = wx * t5[dy];
                            for (int dz = 0; dz < 5; ++dz) {
                                int iz = bz + dz - 2;
                                if ((unsigned)iz >= (unsigned)DIM) continue;
                                float w = wxy * t5[dz];
                                float4 e = src[flatb(ix, iy, iz)];
                                part.x = fmaf(w, e.x, part.x);
                                part.y = fmaf(w, e.y, part.y);
                                part.z = fmaf(w, e.z, part.z);
                                part.w = fmaf(w, e.w, part.w);
                            }
                        }
                    }
                }
            }
            sh[threadIdx.x] = part;
            __syncthreads();
            {
                // finalize split across 4 waves: items 13w..13w+12 (w<3), 12 for w=3
                int w = threadIdx.x >> 6;
                int l = threadIdx.x & 63;
                int nIt = (w < 3) ? 13 : 12;
                int itemIdx = w * 13 + l;
                int item2 = ib * IPB + itemIdx;
                bool valid = (l < nIt) && (item2 < K);
                int bn = -1;
                float4 sv = make_float4(0.f, 0.f, 0.f, 0.f);
                if (valid) {
                    int b = list[item2];
                    float W = src[b].w;     // center count (occupied => sc>0)
                    int base5 = itemIdx * 5;
                    float4 a0 = sh[base5 + 0], a1 = sh[base5 + 1], a2 = sh[base5 + 2];
                    float4 a3 = sh[base5 + 3], a4 = sh[base5 + 4];
                    float sx = a0.x + a1.x + a2.x + a3.x + a4.x;
                    float sy = a0.y + a1.y + a2.y + a3.y + a4.y;
                    float sz = a0.z + a1.z + a2.z + a3.z + a4.z;
                    float sc = a0.w + a1.w + a2.w + a3.w + a4.w;
                    float4 np = make_float4(sx / sc, sy / sc, sz / sc, W);
                    REo[item2] = np;
                    IDXo[b] = item2;
                    if (eposInit) eposInit[item2] = np;
                    if (!lastStep) {
                        bn = flatb(binf(np.x), binf(np.y), binf(np.z));
                        sv = make_float4(W * np.x, W * np.y, W * np.z, W);
                    }
                }
                if (!lastStep) {
                    // run heads within the wave: lane 0, invalid, or key change
                    int pbn = __shfl_up(bn, 1, 64);
                    unsigned f = (l == 0 || !valid || pbn != bn) ? 1u : 0u;
                    // leader = run end (next lane is a head, or last valid lane)
                    unsigned nf = __shfl_down(f, 1, 64);
                    bool leader = valid && (l == nIt - 1 || nf != 0u);
                    // flagged Hillis-Steele segmented inclusive sum (13 lanes -> 4 rounds)
                    #pragma unroll
                    for (int off = 1; off < 16; off <<= 1) {
                        float ox = __shfl_up(sv.x, off, 64);
                        float oy = __shfl_up(sv.y, off, 64);
                        float oz = __shfl_up(sv.z, off, 64);
                        float ow = __shfl_up(sv.w, off, 64);
                        unsigned of = __shfl_up(f, off, 64);
                        if (l >= off) {
                            if (!f) { sv.x += ox; sv.y += oy; sv.z += oz; sv.w += ow; }
                            f |= of;
                        }
                    }
                    if (leader) {
                        float* cell = (float*)&tgt[bn];
                        pk_add(cell + 0, sv.x, sv.y);
                        pk_add(cell + 2, sv.z, sv.w);
                        unsigned bit = 1u << (bn & 31);
                        unsigned word = clT[(unsigned)bn >> 5];  // plain cached read
                        if (!(word & bit)) atomicOr(&clT[(unsigned)bn >> 5], bit);
                    }
                }
            }
            __syncthreads();    // sh reuse
        }
    } else {
        // ---------------- misc blocks ----------------
        int U = (updS > 0) ? (X ? n : *pM0) : 0;
        int CL = clearList ? *pKc : 0;
        int total = U + CL;
        bool done = false;
        if (updS > 1) {
            for (int t = 1; t < updS; ++t) done |= (notConv[t] == 0u);
        }
        int stride = (NF - BC) * blockDim.x;
        for (int idx = (blockIdx.x - BC) * blockDim.x + threadIdx.x; idx < total;
             idx += stride) {
            if (idx < U) {
                int e = idx;
                if (X) {  // per-point step-1 convergence via PIdx
                    float x = X[3 * e + 0], y = X[3 * e + 1], z = X[3 * e + 2];
                    float4 rr = REp[PIdx[e]];
                    float ex = rr.x - x, ey = rr.y - y, ez = rr.z - z;
                    moved |= (fmaf(ex, ex, fmaf(ey, ey, ez * ez)) > TOL2);
                } else if (!done) {  // per-entry update to step-updS position
                    float4 p = epos[e];
                    int j = IDXp[flatb(binf(p.x), binf(p.y), binf(p.z))];
                    float4 rr = REp[j];
                    float ex = rr.x - p.x, ey = rr.y - p.y, ez = rr.z - p.z;
                    moved |= (fmaf(ex, ex, fmaf(ey, ey, ez * ez)) > TOL2);
                    epos[e] = make_float4(rr.x, rr.y, rr.z, p.w);
                }
            } else {
                clearGrid[clearList[idx - U]] = make_float4(0.f, 0.f, 0.f, 0.f);
            }
        }
    }
    if (moved) sFlag = 1;
    __syncthreads();
    if (threadIdx.x == 0 && updS > 0 && sFlag) notConv[updS] = 1u;
}

// ---- mask -> bin-sorted list (block scan, 1 atomic/block), clears mask ----
__launch_bounds__(BLK)
__global__ void k_compactM(unsigned* __restrict__ mask, int* __restrict__ listOut,
                           int* __restrict__ pKout) {
    __shared__ int scan[BLK];
    __shared__ int sBase;
    int i = blockIdx.x * blockDim.x + threadIdx.x;
    unsigned w = (i < CLW) ? mask[i] : 0u;
    if (i < CLW && w) mask[i] = 0u;
    int c = __popc(w);
    scan[threadIdx.x] = c;
    __syncthreads();
    for (int d = 1; d < BLK; d <<= 1) {
        int add = (threadIdx.x >= (unsigned)d) ? scan[threadIdx.x - d] : 0;
        __syncthreads();
        scan[threadIdx.x] += add;
        __syncthreads();
    }
    if (threadIdx.x == BLK - 1) {
        int tot = scan[BLK - 1];
        sBase = tot ? atomicAdd(pKout, tot) : 0;
    }
    __syncthreads();
    int base = sBase + scan[threadIdx.x] - c;
    int bb = i * 32;
    while (w) {
        int b = __ffs(w) - 1;
        listOut[base++] = bb + b;
        w &= w - 1;
    }
}

// ---- per-point output: gather epos via PIdx, optional last hop via REa/IDXa ----
__global__ void k_map(const int* __restrict__ PIdx, int n, const float4* __restrict__ epos,
                      const float4* __restrict__ REa, const int* __restrict__ IDXa,
                      const unsigned* __restrict__ notConv, float* __restrict__ out) {
    bool done = false;
    for (int t = 1; t <= 4; ++t) done |= (notConv[t] == 0u);
    int i = blockIdx.x * blockDim.x + threadIdx.x;
    if (i >= n) return;
    float4 p = epos[PIdx[i]];
    if (!done) {
        float4 rr = REa[IDXa[flatb(binf(p.x), binf(p.y), binf(p.z))]];
        p.x = rr.x; p.y = rr.y; p.z = rr.z;
    }
    out[3 * i + 0] = p.x;
    out[3 * i + 1] = p.y;
    out[3 * i + 2] = p.z;
}

extern "C" void kernel_launch(void* const* d_in, const int* in_sizes, int n_in,
                              void* d_out, int out_size, void* d_ws, size_t ws_size,
                              hipStream_t stream) {
    const float* X = (const float*)d_in[0];
    int n = in_sizes[0] / 3;

    char* ws = (char*)d_ws;
    int*      cnt     = (int*)ws;        // cnt[1..5] list sizes
    unsigned* notConv = (unsigned*)(ws + 32);
    size_t mB = (size_t)CLW * 4;
    size_t gB = (size_t)CELLS * 16;
    unsigned* m0 = (unsigned*)(ws + 256);
    unsigned* m1 = (unsigned*)(ws + 256 + mB);
    float4* A = (float4*)(ws + 256 + 2 * mB);
    float4* B = (float4*)((char*)A + gB);
    float4* C = (float4*)((char*)B + gB);
    int* IDXa = (int*)((char*)C + gB);
    int* IDXb = IDXa + CELLS;
    float4* REa  = (float4*)(IDXb + CELLS);
    float4* REb  = REa + n;
    float4* epos = REb + n;
    int* E0   = (int*)(epos + n);
    int* La   = E0 + n;
    int* Lb   = La + n;
    int* Lc   = Lb + n;
    int* Ld   = Lc + n;
    int* PIdx = Ld + n;
    float4* bucket = (float4*)(PIdx + n);
    int* blockHist = (int*)(bucket + n);
    int* regionPS  = blockHist + NB_A * NREG;

    // meta + masks only (A,B zeroed in histA, C in scatterA)
    hipMemsetAsync(ws, 0, 256 + 2 * mB, stream);

    const int NCM = (CLW + BLK - 1) / BLK;   // compactM blocks

    k_histA<<<NB_A, BLK, 0, stream>>>(X, n, blockHist, A, B);
    k_colscan<<<NREG / BLK, BLK, 0, stream>>>(blockHist, regionPS);
    k_regprefix<<<1, 1024, 0, stream>>>(regionPS);
    k_scatterA<<<NB_A, BLK, 0, stream>>>(X, n, blockHist, regionPS, bucket, C);
    k_binB<<<NREG, BLK, 0, stream>>>(bucket, regionPS, A, E0, PIdx, &cnt[1]);

    // F1: conv A/E0 -> REa/IDXa (+epos init); scatter->B claim m0
    k_fused<<<NF, BLK, 0, stream>>>(A, E0, &cnt[1], REa, IDXa, epos,
                                    B, m0,
                                    0, nullptr, n, nullptr, nullptr, nullptr, nullptr,
                                    nullptr, notConv, nullptr, nullptr, nullptr, 0);
    k_compactM<<<NCM, BLK, 0, stream>>>(m0, La, &cnt[2]);
    // F2: conv B/La -> REb/IDXb; scatter->C claim m1; upd1 via PIdx (REa); clear A via E0
    k_fused<<<NF, BLK, 0, stream>>>(B, La, &cnt[2], REb, IDXb, nullptr,
                                    C, m1,
                                    1, X, n, PIdx, REa, IDXa, &cnt[1], nullptr,
                                    notConv, E0, &cnt[1], A, 0);
    k_compactM<<<NCM, BLK, 0, stream>>>(m1, Lb, &cnt[3]);
    // F3: conv C/Lb -> REa/IDXa; scatter->A claim m0; upd2 (REb/IDXb); clear B via La
    k_fused<<<NF, BLK, 0, stream>>>(C, Lb, &cnt[3], REa, IDXa, nullptr,
                                    A, m0,
                                    2, nullptr, n, nullptr, REb, IDXb, &cnt[1], epos,
                                    notConv, La, &cnt[2], B, 0);
    k_compactM<<<NCM, BLK, 0, stream>>>(m0, Lc, &cnt[4]);
    // F4: conv A/Lc -> REb/IDXb; scatter->B claim m1; upd3 (REa/IDXa)
    k_fused<<<NF, BLK, 0, stream>>>(A, Lc, &cnt[4], REb, IDXb, nullptr,
                                    B, m1,
                                    3, nullptr, n, nullptr, REa, IDXa, &cnt[1], epos,
                                    notConv, nullptr, nullptr, nullptr, 0);
    k_compactM<<<NCM, BLK, 0, stream>>>(m1, Ld, &cnt[5]);
    // F5: conv B/Ld -> REa/IDXa (conv only); upd4 (REb/IDXb)
    k_fused<<<NF, BLK, 0, stream>>>(B, Ld, &cnt[5], REa, IDXa, nullptr,
                                    nullptr, nullptr,
                                    4, nullptr, n, nullptr, REb, IDXb, &cnt[1], epos,
                                    notConv, nullptr, nullptr, nullptr, 1);

    k_map<<<(n + BLK - 1) / BLK, BLK, 0, stream>>>(PIdx, n, epos, REa, IDXa,
                                                   notConv, (float*)d_out);
}